// Round 11
// baseline (73.203 us; speedup 1.0000x reference)
//
#include <hip/hip_runtime.h>
#include <hip/hip_fp16.h>

#define NTHREADS 256
#define NBLOCKS 1024     // main kernel: 262K threads x 8 edges = ~2 iterations
#define FB_NBLOCKS 2048
#define NB 1024          // lerp intervals; nodes 0..NB
#define NBP 1040         // padded per-array stride (floats)

// Folded constants:
//   KTOT = sqrt(2) * 1.14136 * e^2     (sqrt(10) in emb cancels /sqrt(10) before relu;
//                                       relu positively homogeneous -> sqrt(2) folds in)
//   CL_l = PATH_C_l * 0.25 * (1/sqrt(10))   (w = h@W2/sqrt(16), node scale 1/sqrt(10))
//   SH scale factors (S3, S5*S3, S5, 0.5*S5*S3) folded into the packed fp16 node table.
//   w_l(r)*CL_l tabulated on 1025 r-nodes (w==0 for r>=1: basis support dies at cutoff).
#define KTOT 11.9269705f
#define CL0  0.04564355f
#define CL1  0.02635231f
#define CL2  0.02041241f
#define S3   1.7320508f
#define S5   2.2360680f

__device__ __forceinline__ float fast_rcp(float x) { return __builtin_amdgcn_rcpf(x); }

// ---------- prep 1: node_feats [N][9] f32 -> merged table, 3 nodes per 64B line ----------
// line l (64B): [slot0 8xfp16 | slot1 8xfp16 | slot2 8xfp16 | h8_0 h8_1 h8_2 (2B each) | 10B pad]
// node n: l = n/3, s = n%3; 16B at l*64+s*16 (16B-aligned), 9th half at l*64+48+2s.
__global__ __launch_bounds__(256) void pack_feats_merged(
    const float* __restrict__ nf, char* __restrict__ tab, int n_nodes)
{
    const int n = blockIdx.x * 256 + threadIdx.x;
    if (n >= n_nodes) return;
    const float* f = nf + 9 * (size_t)n;
    unsigned u[4];
    {
        __half2 h; h.x = __float2half_rn(f[0]);             h.y = __float2half_rn(f[1] * S3);
        u[0] = *reinterpret_cast<unsigned*>(&h);
    }
    {
        __half2 h; h.x = __float2half_rn(f[2] * S3);        h.y = __float2half_rn(f[3] * S3);
        u[1] = *reinterpret_cast<unsigned*>(&h);
    }
    {
        __half2 h; h.x = __float2half_rn(f[4] * (S5 * S3)); h.y = __float2half_rn(f[5] * (S5 * S3));
        u[2] = *reinterpret_cast<unsigned*>(&h);
    }
    {
        __half2 h; h.x = __float2half_rn(f[6] * S5);        h.y = __float2half_rn(f[7] * (S5 * S3));
        u[3] = *reinterpret_cast<unsigned*>(&h);
    }
    const unsigned l = (unsigned)n / 3u;
    const unsigned s = (unsigned)n - 3u * l;
    char* line = tab + ((size_t)l << 6);
    *reinterpret_cast<uint4*>(line + (s << 4)) = make_uint4(u[0], u[1], u[2], u[3]);
    const __half h8 = __float2half_rn(f[8] * (0.5f * S5 * S3));
    *reinterpret_cast<unsigned short*>(line + 48 + (s << 1)) =
        *reinterpret_cast<const unsigned short*>(&h8);
}

// ---------- prep 2: tabulate w_l(r)*CL_l at r = i/NB, i = 0..NB (identical to R9) ----------
__global__ __launch_bounds__(256) void build_wtable_kernel(
    const float* __restrict__ W1, const float* __restrict__ W2,
    float* __restrict__ wtab)   // [3][NBP] SoA
{
    const int idx = blockIdx.x * 256 + threadIdx.x;
    if (idx > NB) return;
    const float r = (float)idx * (1.0f / (float)NB);

    const float t    = 11.0f * r;
    const int   k0   = (int)t;
    const float frac = t - (float)k0;
    float ea = 0.0f, eb = 0.0f;
    if (k0 >= 1 && k0 <= 10) {
        const float da = fmaf(-frac, frac, 1.0f);
        if (da > 0.0226f) ea = KTOT * __expf(-2.0f * fast_rcp(da));
    }
    if (k0 <= 9) {
        const float db = frac * (2.0f - frac);
        if (db > 0.0226f) eb = KTOT * __expf(-2.0f * fast_rcp(db));
    }
    const int ra = min(max(k0 - 1, 0), 9);
    const int rb = min(k0, 9);

    float w0 = 0.0f, w1 = 0.0f, w2 = 0.0f;
#pragma unroll
    for (int j = 0; j < 16; ++j) {
        const float h = fmaxf(fmaf(ea, W1[ra * 16 + j], eb * W1[rb * 16 + j]), 0.0f);
        w0 = fmaf(h, W2[j * 3 + 0], w0);
        w1 = fmaf(h, W2[j * 3 + 1], w1);
        w2 = fmaf(h, W2[j * 3 + 2], w2);
    }
    wtab[idx]           = w0 * CL0;
    wtab[NBP + idx]     = w1 * CL1;
    wtab[2 * NBP + idx] = w2 * CL2;
}

__device__ __forceinline__ float2 cvt2(unsigned u) {
    __half2 h = *reinterpret_cast<__half2*>(&u);
    return __half22float2(h);
}

// ---------- single-line node gather ----------
__device__ __forceinline__ void load_node(
    const char* __restrict__ tab, unsigned n, uint4& g, float& g8)
{
    const unsigned l = n / 3u;
    const unsigned s = n - 3u * l;
    const char* line = tab + ((size_t)l << 6);
    g = *reinterpret_cast<const uint4*>(line + (s << 4));        // 16B, 16B-aligned
    const unsigned short hb =
        *reinterpret_cast<const unsigned short*>(line + 48 + (s << 1)); // same 64B line
    const __half hh = *reinterpret_cast<const __half*>(&hb);
    g8 = __half2float(hh);
}

// ---------- per-edge term via LUT (identical math to R9) ----------
__device__ __forceinline__ float edge_term_lut(
    float vx, float vy, float vz, uint4 g0, float f8p,
    const float* __restrict__ sw)
{
    const float r2 = fmaf(vx, vx, fmaf(vy, vy, vz * vz));
    const float rs = rsqrtf(fmaxf(r2, 1e-24f));
    const float r  = r2 * rs;
    const float x = vx * rs, y = vy * rs, z = vz * rs;

    const float tb = fminf(r, 1.0f) * (float)NB;
    const int   i  = min((int)tb, NB - 1);
    const float fb = tb - (float)i;
    const float w0a = sw[i],           w0b = sw[i + 1];
    const float w1a = sw[NBP + i],     w1b = sw[NBP + i + 1];
    const float w2a = sw[2 * NBP + i], w2b = sw[2 * NBP + i + 1];
    const float wv0 = fmaf(fb, w0b - w0a, w0a);
    const float wv1 = fmaf(fb, w1b - w1a, w1a);
    const float wv2 = fmaf(fb, w2b - w2a, w2a);

    const float2 f01 = cvt2(g0.x);   // f0,       S3*f1
    const float2 f23 = cvt2(g0.y);   // S3*f2,    S3*f3
    const float2 f45 = cvt2(g0.z);   // S5S3*f4,  S5S3*f5
    const float2 f67 = cvt2(g0.w);   // S5*f6,    S5S3*f7

    const float dots0 = f01.x;
    const float dots1 = fmaf(f01.y, x, fmaf(f23.x, y, f23.y * z));
    const float xx = x * x, yy = y * y, zz = z * z;
    const float dots2 = fmaf(f45.x, x * z, fmaf(f45.y, x * y,
                        fmaf(f67.x, fmaf(-0.5f, xx + zz, yy),
                        fmaf(f67.y, y * z, f8p * (zz - xx)))));

    return fmaf(wv0, dots0, fmaf(wv1, dots1, wv2 * dots2));
}

// ---------- main: grid-stride, 8 edges/iter, one gather line per edge ----------
__global__ __launch_bounds__(NTHREADS) void edge_sum_merged(
    const float4* __restrict__ ev4,
    const int4*   __restrict__ src4,
    const char*   __restrict__ tab,
    const float*  __restrict__ wtab,
    float*        __restrict__ block_sums,
    int n_edges)
{
    __shared__ float sw[3 * NBP];
    const int tid = threadIdx.x;
    for (int i = tid; i < 3 * NBP; i += NTHREADS) sw[i] = wtab[i];
    __syncthreads();

    float acc = 0.0f;
    const int n_units = (n_edges + 7) >> 3;
    const int stride = gridDim.x * blockDim.x;
    for (int u = blockIdx.x * blockDim.x + tid; u < n_units; u += stride) {
        const int e0 = u << 3;
        if (e0 + 8 <= n_edges) {
            // stream: 6 x float4 (24 floats = 8 edges) + 2 x int4, all independent
            const float4 v0 = ev4[6 * (size_t)u + 0];
            const float4 v1 = ev4[6 * (size_t)u + 1];
            const float4 v2 = ev4[6 * (size_t)u + 2];
            const float4 v3 = ev4[6 * (size_t)u + 3];
            const float4 v4 = ev4[6 * (size_t)u + 4];
            const float4 v5 = ev4[6 * (size_t)u + 5];
            const int4 sA = src4[2 * (size_t)u + 0];
            const int4 sB = src4[2 * (size_t)u + 1];
            // gathers: one 64B line each (16B + 2B from same line)
            uint4 g0, g1, g2, g3, g4, g5, g6, g7;
            float h0, h1, h2, h3, h4, h5, h6, h7;
            load_node(tab, (unsigned)sA.x, g0, h0);
            load_node(tab, (unsigned)sA.y, g1, h1);
            load_node(tab, (unsigned)sA.z, g2, h2);
            load_node(tab, (unsigned)sA.w, g3, h3);
            load_node(tab, (unsigned)sB.x, g4, h4);
            load_node(tab, (unsigned)sB.y, g5, h5);
            load_node(tab, (unsigned)sB.z, g6, h6);
            load_node(tab, (unsigned)sB.w, g7, h7);

            acc += edge_term_lut(v0.x, v0.y, v0.z, g0, h0, sw);
            acc += edge_term_lut(v0.w, v1.x, v1.y, g1, h1, sw);
            acc += edge_term_lut(v1.z, v1.w, v2.x, g2, h2, sw);
            acc += edge_term_lut(v2.y, v2.z, v2.w, g3, h3, sw);
            acc += edge_term_lut(v3.x, v3.y, v3.z, g4, h4, sw);
            acc += edge_term_lut(v3.w, v4.x, v4.y, g5, h5, sw);
            acc += edge_term_lut(v4.z, v4.w, v5.x, g6, h6, sw);
            acc += edge_term_lut(v5.y, v5.z, v5.w, g7, h7, sw);
        } else {
            const float* evf  = reinterpret_cast<const float*>(ev4);
            const int*   srci = reinterpret_cast<const int*>(src4);
            for (int e = e0; e < n_edges; ++e) {
                uint4 gg; float hh;
                load_node(tab, (unsigned)srci[e], gg, hh);
                acc += edge_term_lut(evf[3 * (size_t)e], evf[3 * (size_t)e + 1],
                                     evf[3 * (size_t)e + 2], gg, hh, sw);
            }
        }
    }

    // deterministic block reduction
#pragma unroll
    for (int off = 1; off < 64; off <<= 1)
        acc += __shfl_xor(acc, off, 64);
    __shared__ float wsum[NTHREADS / 64];
    const int lane = tid & 63, wid = tid >> 6;
    if (lane == 0) wsum[wid] = acc;
    __syncthreads();
    if (tid == 0) {
        float ssum = 0.0f;
#pragma unroll
        for (int w = 0; w < NTHREADS / 64; ++w) ssum += wsum[w];
        block_sums[blockIdx.x] = ssum;
    }
}

// ---------- fallback (round-2 proven path, exact math, f32 scalar gather) ----------
__global__ __launch_bounds__(NTHREADS) void edge_sum_fallback(
    const float* __restrict__ node_feats,
    const float* __restrict__ edge_vec,
    const float* __restrict__ W1,
    const float* __restrict__ W2,
    const int*   __restrict__ edge_src,
    float*       __restrict__ block_sums,
    int n_edges)
{
    __shared__ float4 sW1[10][5];
    float* sW1f = reinterpret_cast<float*>(sW1);
    const int tid = threadIdx.x;
    if (tid < 160) {
        sW1f[(tid >> 4) * 20 + (tid & 15)] = W1[tid];
    } else if (tid < 200) {
        const int i = tid - 160;
        sW1f[(i >> 2) * 20 + 16 + (i & 3)] = 0.0f;
    }
    __syncthreads();

    float w2r[16][3];
#pragma unroll
    for (int j = 0; j < 16; ++j) {
        w2r[j][0] = W2[j * 3 + 0] * CL0;
        w2r[j][1] = W2[j * 3 + 1] * CL1;
        w2r[j][2] = W2[j * 3 + 2] * CL2;
    }

    float acc = 0.0f;
    const int stride = gridDim.x * blockDim.x;
    for (int e = blockIdx.x * blockDim.x + tid; e < n_edges; e += stride) {
        const float vx = edge_vec[3 * (size_t)e + 0];
        const float vy = edge_vec[3 * (size_t)e + 1];
        const float vz = edge_vec[3 * (size_t)e + 2];
        const int   src = edge_src[e];
        const float* f = node_feats + 9 * (size_t)src;
        const float r2 = fmaf(vx, vx, fmaf(vy, vy, vz * vz));
        const float rs = rsqrtf(fmaxf(r2, 1e-24f));
        const float r  = r2 * rs;
        const float x = vx * rs, y = vy * rs, z = vz * rs;
        const float t    = 11.0f * r;
        const int   k0   = (int)t;
        const float frac = t - (float)k0;
        float ea = 0.0f, eb = 0.0f;
        if (k0 >= 1 && k0 <= 10) {
            const float da = fmaf(-frac, frac, 1.0f);
            if (da > 0.0226f) ea = KTOT * __expf(-2.0f * fast_rcp(da));
        }
        if (k0 <= 9) {
            const float db = frac * (2.0f - frac);
            if (db > 0.0226f) eb = KTOT * __expf(-2.0f * fast_rcp(db));
        }
        const int ra = min(max(k0 - 1, 0), 9);
        const int rb = min(k0, 9);
        const float4* rowA = &sW1[ra][0];
        const float4* rowB = &sW1[rb][0];
        float wv0 = 0.0f, wv1 = 0.0f, wv2 = 0.0f;
#pragma unroll
        for (int q = 0; q < 4; ++q) {
            const float4 A = rowA[q];
            const float4 B = rowB[q];
            float h;
            h = fmaxf(fmaf(ea, A.x, eb * B.x), 0.0f);
            wv0 = fmaf(h, w2r[4 * q + 0][0], wv0); wv1 = fmaf(h, w2r[4 * q + 0][1], wv1); wv2 = fmaf(h, w2r[4 * q + 0][2], wv2);
            h = fmaxf(fmaf(ea, A.y, eb * B.y), 0.0f);
            wv0 = fmaf(h, w2r[4 * q + 1][0], wv0); wv1 = fmaf(h, w2r[4 * q + 1][1], wv1); wv2 = fmaf(h, w2r[4 * q + 1][2], wv2);
            h = fmaxf(fmaf(ea, A.z, eb * B.z), 0.0f);
            wv0 = fmaf(h, w2r[4 * q + 2][0], wv0); wv1 = fmaf(h, w2r[4 * q + 2][1], wv1); wv2 = fmaf(h, w2r[4 * q + 2][2], wv2);
            h = fmaxf(fmaf(ea, A.w, eb * B.w), 0.0f);
            wv0 = fmaf(h, w2r[4 * q + 3][0], wv0); wv1 = fmaf(h, w2r[4 * q + 3][1], wv1); wv2 = fmaf(h, w2r[4 * q + 3][2], wv2);
        }
        const float f0 = f[0], f1 = f[1], f2 = f[2], f3 = f[3], f4 = f[4];
        const float f5 = f[5], f6 = f[6], f7 = f[7], f8 = f[8];
        const float dots0 = f0;
        const float dots1 = S3 * fmaf(f1, x, fmaf(f2, y, f3 * z));
        const float xx = x * x, yy = y * y, zz = z * z;
        const float sh20 = S5 * S3 * x * z;
        const float sh21 = S5 * S3 * x * y;
        const float sh22 = S5 * (yy - 0.5f * (xx + zz));
        const float sh23 = S5 * S3 * y * z;
        const float sh24 = S5 * 0.5f * S3 * (zz - xx);
        const float dots2 = fmaf(f4, sh20, fmaf(f5, sh21, fmaf(f6, sh22, fmaf(f7, sh23, f8 * sh24))));
        acc = fmaf(wv0, dots0, acc);
        acc = fmaf(wv1, dots1, acc);
        acc = fmaf(wv2, dots2, acc);
    }
#pragma unroll
    for (int off = 1; off < 64; off <<= 1)
        acc += __shfl_xor(acc, off, 64);
    __shared__ float wsum[NTHREADS / 64];
    const int lane = tid & 63, wid = tid >> 6;
    if (lane == 0) wsum[wid] = acc;
    __syncthreads();
    if (tid == 0) {
        float ssum = 0.0f;
#pragma unroll
        for (int w = 0; w < NTHREADS / 64; ++w) ssum += wsum[w];
        block_sums[blockIdx.x] = ssum;
    }
}

__global__ __launch_bounds__(256) void final_reduce_kernel(
    const float* __restrict__ block_sums, float* __restrict__ out, int n)
{
    const int tid = threadIdx.x;
    float acc = 0.0f;
    for (int i = tid; i < n; i += 256) acc += block_sums[i];
#pragma unroll
    for (int off = 1; off < 64; off <<= 1)
        acc += __shfl_xor(acc, off, 64);
    __shared__ float wsum[4];
    if ((tid & 63) == 0) wsum[tid >> 6] = acc;
    __syncthreads();
    if (tid == 0) out[0] = wsum[0] + wsum[1] + wsum[2] + wsum[3];
}

extern "C" void kernel_launch(void* const* d_in, const int* in_sizes, int n_in,
                              void* d_out, int out_size, void* d_ws, size_t ws_size,
                              hipStream_t stream) {
    const float* node_feats = (const float*)d_in[0];
    const float* edge_vec   = (const float*)d_in[1];
    const float* W1         = (const float*)d_in[2];
    const float* W2         = (const float*)d_in[3];
    const int*   edge_src   = (const int*)d_in[4];
    // d_in[5] (edge_dst) unused: segment_sum().sum() == plain sum over edges.
    const int n_edges = in_sizes[4];
    const int n_nodes = in_sizes[0] / 9;

    // ws layout: [block_sums: 32KB][wtab: 3*NBP f32][merged table: ceil(N/3)*64B]
    float* block_sums = (float*)d_ws;
    const size_t wtab_off = 32768;
    const size_t tab_off  = wtab_off + ((3 * NBP * 4 + 255) & ~255);   // 256-aligned
    const size_t n_lines  = (size_t)((n_nodes + 2) / 3);
    const size_t need     = tab_off + n_lines * 64;

    if (ws_size >= need) {
        float* wtab = (float*)((char*)d_ws + wtab_off);
        char*  tab  = (char*)d_ws + tab_off;
        pack_feats_merged<<<(n_nodes + 255) / 256, 256, 0, stream>>>(
            node_feats, tab, n_nodes);
        build_wtable_kernel<<<(NB + 256) / 256, 256, 0, stream>>>(W1, W2, wtab);
        edge_sum_merged<<<NBLOCKS, NTHREADS, 0, stream>>>(
            (const float4*)edge_vec, (const int4*)edge_src, tab,
            wtab, block_sums, n_edges);
        final_reduce_kernel<<<1, 256, 0, stream>>>(block_sums, (float*)d_out, NBLOCKS);
    } else {
        edge_sum_fallback<<<FB_NBLOCKS, NTHREADS, 0, stream>>>(
            node_feats, edge_vec, W1, W2, edge_src, block_sums, n_edges);
        final_reduce_kernel<<<1, 256, 0, stream>>>(block_sums, (float*)d_out, FB_NBLOCKS);
    }
}

// Round 13
// 46.793 us; speedup vs baseline: 1.5644x; 1.5644x over previous
//
#include <hip/hip_runtime.h>
#include <hip/hip_fp16.h>

#define NTHREADS 256
#define NBLOCKS 2048
#define FB_NBLOCKS 2048
#define NB 1024          // lerp intervals; nodes 0..NB
#define NBP 1040         // padded per-array stride (floats)

// Folded constants (same derivation as R9):
//   KTOT = sqrt(2) * 1.14136 * e^2 ; CL_l = PATH_C_l * 0.25 / sqrt(10)
//   SH scales folded into packed node values; w_l(r)*CL_l in the r-LUT.
#define KTOT 11.9269705f
#define CL0  0.04564355f
#define CL1  0.02635231f
#define CL2  0.02041241f
#define S3   1.7320508f
#define S5   2.2360680f

__device__ __forceinline__ float fast_rcp(float x) { return __builtin_amdgcn_rcpf(x); }

// ---------- prep 1: node_feats [N][9] f32 -> 16B/node packed record ----------
// bits [0..112): f1s..f8s as fp14 (fp16 rounded, >>2) at 14-bit stride
// bits [112..128): f0 as full fp16
__global__ __launch_bounds__(256) void pack_feats_14(
    const float* __restrict__ nf, uint4* __restrict__ tab, int n_nodes)
{
    const int n = blockIdx.x * 256 + threadIdx.x;
    if (n >= n_nodes) return;
    const float* f = nf + 9 * (size_t)n;
    const float scale[9] = { 1.0f, S3, S3, S3, S5 * S3, S5 * S3, S5, S5 * S3,
                             0.5f * S5 * S3 };
    unsigned short hs[9];
#pragma unroll
    for (int i = 0; i < 9; ++i) {
        const __half h = __float2half_rn(f[i] * scale[i]);
        hs[i] = *reinterpret_cast<const unsigned short*>(&h);
    }
    unsigned long long c[9];
#pragma unroll
    for (int i = 1; i < 9; ++i)
        c[i] = (unsigned long long)(((unsigned)hs[i] + 2u) >> 2) & 0x3FFFull;
    const unsigned long long lo =
        c[1] | (c[2] << 14) | (c[3] << 28) | (c[4] << 42) | (c[5] << 56);
    const unsigned long long hi =
        (c[5] >> 8) | (c[6] << 6) | (c[7] << 20) | (c[8] << 34) |
        ((unsigned long long)hs[0] << 48);
    tab[n] = make_uint4((unsigned)lo, (unsigned)(lo >> 32),
                        (unsigned)hi, (unsigned)(hi >> 32));
}

// ---------- prep 2: tabulate w_l(r)*CL_l at r = i/NB (identical to R9) ----------
__global__ __launch_bounds__(256) void build_wtable_kernel(
    const float* __restrict__ W1, const float* __restrict__ W2,
    float* __restrict__ wtab)   // [3][NBP] SoA
{
    const int idx = blockIdx.x * 256 + threadIdx.x;
    if (idx > NB) return;
    const float r = (float)idx * (1.0f / (float)NB);

    const float t    = 11.0f * r;
    const int   k0   = (int)t;
    const float frac = t - (float)k0;
    float ea = 0.0f, eb = 0.0f;
    if (k0 >= 1 && k0 <= 10) {
        const float da = fmaf(-frac, frac, 1.0f);
        if (da > 0.0226f) ea = KTOT * __expf(-2.0f * fast_rcp(da));
    }
    if (k0 <= 9) {
        const float db = frac * (2.0f - frac);
        if (db > 0.0226f) eb = KTOT * __expf(-2.0f * fast_rcp(db));
    }
    const int ra = min(max(k0 - 1, 0), 9);
    const int rb = min(k0, 9);

    float w0 = 0.0f, w1 = 0.0f, w2 = 0.0f;
#pragma unroll
    for (int j = 0; j < 16; ++j) {
        const float h = fmaxf(fmaf(ea, W1[ra * 16 + j], eb * W1[rb * 16 + j]), 0.0f);
        w0 = fmaf(h, W2[j * 3 + 0], w0);
        w1 = fmaf(h, W2[j * 3 + 1], w1);
        w2 = fmaf(h, W2[j * 3 + 2], w2);
    }
    wtab[idx]           = w0 * CL0;
    wtab[NBP + idx]     = w1 * CL1;
    wtab[2 * NBP + idx] = w2 * CL2;
}

// fp14 code (14 bits) -> f32 via fp16 bit pattern
__device__ __forceinline__ float cvt14(unsigned c) {
    __half_raw hr; hr.x = (unsigned short)(c << 2);
    return __half2float(*reinterpret_cast<const __half*>(&hr));
}
__device__ __forceinline__ float cvt16(unsigned c) {
    __half_raw hr; hr.x = (unsigned short)c;
    return __half2float(*reinterpret_cast<const __half*>(&hr));
}
__device__ __forceinline__ unsigned alignb(unsigned hi, unsigned lo, int s) {
    return (lo >> s) | (hi << (32 - s));
}

// ---------- per-edge term: LUT for w(r), packed node record g ----------
__device__ __forceinline__ float edge_term_lut(
    float vx, float vy, float vz, uint4 g,
    const float* __restrict__ sw)
{
    const float r2 = fmaf(vx, vx, fmaf(vy, vy, vz * vz));
    const float rs = rsqrtf(fmaxf(r2, 1e-24f));
    const float r  = r2 * rs;
    const float x = vx * rs, y = vy * rs, z = vz * rs;

    const float tb = fminf(r, 1.0f) * (float)NB;
    const int   i  = min((int)tb, NB - 1);
    const float fb = tb - (float)i;
    const float w0a = sw[i],           w0b = sw[i + 1];
    const float w1a = sw[NBP + i],     w1b = sw[NBP + i + 1];
    const float w2a = sw[2 * NBP + i], w2b = sw[2 * NBP + i + 1];
    const float wv0 = fmaf(fb, w0b - w0a, w0a);
    const float wv1 = fmaf(fb, w1b - w1a, w1a);
    const float wv2 = fmaf(fb, w2b - w2a, w2a);

    // unpack 9 values from 128 bits
    const float fv1 = cvt14(g.x & 0x3FFFu);
    const float fv2 = cvt14((g.x >> 14) & 0x3FFFu);
    const float fv3 = cvt14(alignb(g.y, g.x, 28) & 0x3FFFu);
    const float fv4 = cvt14((g.y >> 10) & 0x3FFFu);
    const float fv5 = cvt14(alignb(g.z, g.y, 24) & 0x3FFFu);
    const float fv6 = cvt14((g.z >> 6) & 0x3FFFu);
    const float fv7 = cvt14(alignb(g.w, g.z, 20) & 0x3FFFu);
    const float fv8 = cvt14((g.w >> 2) & 0x3FFFu);
    const float f0  = cvt16(g.w >> 16);

    const float dots0 = f0;
    const float dots1 = fmaf(fv1, x, fmaf(fv2, y, fv3 * z));
    const float xx = x * x, yy = y * y, zz = z * z;
    const float dots2 = fmaf(fv4, x * z, fmaf(fv5, x * y,
                        fmaf(fv6, fmaf(-0.5f, xx + zz, yy),
                        fmaf(fv7, y * z, fv8 * (zz - xx)))));

    return fmaf(wv0, dots0, fmaf(wv1, dots1, wv2 * dots2));
}

// ---------- main: R9 structure (2048x256, 4 edges/iter), ONE 16B gather/edge ----------
__global__ __launch_bounds__(NTHREADS) void edge_sum_p14(
    const float4* __restrict__ ev4,
    const int4*   __restrict__ src4,
    const uint4*  __restrict__ tab,
    const float*  __restrict__ wtab,
    float*        __restrict__ block_sums,
    int n_edges)
{
    __shared__ float sw[3 * NBP];
    const int tid = threadIdx.x;
    for (int i = tid; i < 3 * NBP; i += NTHREADS) sw[i] = wtab[i];
    __syncthreads();

    float acc = 0.0f;
    const int n_groups = (n_edges + 3) >> 2;
    const int stride = gridDim.x * blockDim.x;
    for (int g = blockIdx.x * blockDim.x + tid; g < n_groups; g += stride) {
        const int e0 = g << 2;
        if (e0 + 3 < n_edges) {
            const float4 a = ev4[3 * (size_t)g + 0];
            const float4 b = ev4[3 * (size_t)g + 1];
            const float4 c = ev4[3 * (size_t)g + 2];
            const int4   s = src4[g];
            const uint4 g0 = tab[s.x];
            const uint4 g1 = tab[s.y];
            const uint4 g2 = tab[s.z];
            const uint4 g3 = tab[s.w];
            acc += edge_term_lut(a.x, a.y, a.z, g0, sw);
            acc += edge_term_lut(a.w, b.x, b.y, g1, sw);
            acc += edge_term_lut(b.z, b.w, c.x, g2, sw);
            acc += edge_term_lut(c.y, c.z, c.w, g3, sw);
        } else {
            const float* evf  = reinterpret_cast<const float*>(ev4);
            const int*   srci = reinterpret_cast<const int*>(src4);
            for (int e = e0; e < n_edges; ++e) {
                acc += edge_term_lut(evf[3 * (size_t)e], evf[3 * (size_t)e + 1],
                                     evf[3 * (size_t)e + 2], tab[srci[e]], sw);
            }
        }
    }

    // deterministic block reduction
#pragma unroll
    for (int off = 1; off < 64; off <<= 1)
        acc += __shfl_xor(acc, off, 64);
    __shared__ float wsum[NTHREADS / 64];
    const int lane = tid & 63, wid = tid >> 6;
    if (lane == 0) wsum[wid] = acc;
    __syncthreads();
    if (tid == 0) {
        float ssum = 0.0f;
#pragma unroll
        for (int w = 0; w < NTHREADS / 64; ++w) ssum += wsum[w];
        block_sums[blockIdx.x] = ssum;
    }
}

// ---------- fallback (round-2 proven path, exact math, f32 scalar gather) ----------
__global__ __launch_bounds__(NTHREADS) void edge_sum_fallback(
    const float* __restrict__ node_feats,
    const float* __restrict__ edge_vec,
    const float* __restrict__ W1,
    const float* __restrict__ W2,
    const int*   __restrict__ edge_src,
    float*       __restrict__ block_sums,
    int n_edges)
{
    __shared__ float4 sW1[10][5];
    float* sW1f = reinterpret_cast<float*>(sW1);
    const int tid = threadIdx.x;
    if (tid < 160) {
        sW1f[(tid >> 4) * 20 + (tid & 15)] = W1[tid];
    } else if (tid < 200) {
        const int i = tid - 160;
        sW1f[(i >> 2) * 20 + 16 + (i & 3)] = 0.0f;
    }
    __syncthreads();

    float w2r[16][3];
#pragma unroll
    for (int j = 0; j < 16; ++j) {
        w2r[j][0] = W2[j * 3 + 0] * CL0;
        w2r[j][1] = W2[j * 3 + 1] * CL1;
        w2r[j][2] = W2[j * 3 + 2] * CL2;
    }

    float acc = 0.0f;
    const int stride = gridDim.x * blockDim.x;
    for (int e = blockIdx.x * blockDim.x + tid; e < n_edges; e += stride) {
        const float vx = edge_vec[3 * (size_t)e + 0];
        const float vy = edge_vec[3 * (size_t)e + 1];
        const float vz = edge_vec[3 * (size_t)e + 2];
        const int   src = edge_src[e];
        const float* f = node_feats + 9 * (size_t)src;
        const float r2 = fmaf(vx, vx, fmaf(vy, vy, vz * vz));
        const float rs = rsqrtf(fmaxf(r2, 1e-24f));
        const float r  = r2 * rs;
        const float x = vx * rs, y = vy * rs, z = vz * rs;
        const float t    = 11.0f * r;
        const int   k0   = (int)t;
        const float frac = t - (float)k0;
        float ea = 0.0f, eb = 0.0f;
        if (k0 >= 1 && k0 <= 10) {
            const float da = fmaf(-frac, frac, 1.0f);
            if (da > 0.0226f) ea = KTOT * __expf(-2.0f * fast_rcp(da));
        }
        if (k0 <= 9) {
            const float db = frac * (2.0f - frac);
            if (db > 0.0226f) eb = KTOT * __expf(-2.0f * fast_rcp(db));
        }
        const int ra = min(max(k0 - 1, 0), 9);
        const int rb = min(k0, 9);
        const float4* rowA = &sW1[ra][0];
        const float4* rowB = &sW1[rb][0];
        float wv0 = 0.0f, wv1 = 0.0f, wv2 = 0.0f;
#pragma unroll
        for (int q = 0; q < 4; ++q) {
            const float4 A = rowA[q];
            const float4 B = rowB[q];
            float h;
            h = fmaxf(fmaf(ea, A.x, eb * B.x), 0.0f);
            wv0 = fmaf(h, w2r[4 * q + 0][0], wv0); wv1 = fmaf(h, w2r[4 * q + 0][1], wv1); wv2 = fmaf(h, w2r[4 * q + 0][2], wv2);
            h = fmaxf(fmaf(ea, A.y, eb * B.y), 0.0f);
            wv0 = fmaf(h, w2r[4 * q + 1][0], wv0); wv1 = fmaf(h, w2r[4 * q + 1][1], wv1); wv2 = fmaf(h, w2r[4 * q + 1][2], wv2);
            h = fmaxf(fmaf(ea, A.z, eb * B.z), 0.0f);
            wv0 = fmaf(h, w2r[4 * q + 2][0], wv0); wv1 = fmaf(h, w2r[4 * q + 2][1], wv1); wv2 = fmaf(h, w2r[4 * q + 2][2], wv2);
            h = fmaxf(fmaf(ea, A.w, eb * B.w), 0.0f);
            wv0 = fmaf(h, w2r[4 * q + 3][0], wv0); wv1 = fmaf(h, w2r[4 * q + 3][1], wv1); wv2 = fmaf(h, w2r[4 * q + 3][2], wv2);
        }
        const float f0 = f[0], f1 = f[1], f2 = f[2], f3 = f[3], f4 = f[4];
        const float f5 = f[5], f6 = f[6], f7 = f[7], f8 = f[8];
        const float dots0 = f0;
        const float dots1 = S3 * fmaf(f1, x, fmaf(f2, y, f3 * z));
        const float xx = x * x, yy = y * y, zz = z * z;
        const float sh20 = S5 * S3 * x * z;
        const float sh21 = S5 * S3 * x * y;
        const float sh22 = S5 * (yy - 0.5f * (xx + zz));
        const float sh23 = S5 * S3 * y * z;
        const float sh24 = S5 * 0.5f * S3 * (zz - xx);
        const float dots2 = fmaf(f4, sh20, fmaf(f5, sh21, fmaf(f6, sh22, fmaf(f7, sh23, f8 * sh24))));
        acc = fmaf(wv0, dots0, acc);
        acc = fmaf(wv1, dots1, acc);
        acc = fmaf(wv2, dots2, acc);
    }
#pragma unroll
    for (int off = 1; off < 64; off <<= 1)
        acc += __shfl_xor(acc, off, 64);
    __shared__ float wsum[NTHREADS / 64];
    const int lane = tid & 63, wid = tid >> 6;
    if (lane == 0) wsum[wid] = acc;
    __syncthreads();
    if (tid == 0) {
        float ssum = 0.0f;
#pragma unroll
        for (int w = 0; w < NTHREADS / 64; ++w) ssum += wsum[w];
        block_sums[blockIdx.x] = ssum;
    }
}

__global__ __launch_bounds__(256) void final_reduce_kernel(
    const float* __restrict__ block_sums, float* __restrict__ out, int n)
{
    const int tid = threadIdx.x;
    float acc = 0.0f;
    for (int i = tid; i < n; i += 256) acc += block_sums[i];
#pragma unroll
    for (int off = 1; off < 64; off <<= 1)
        acc += __shfl_xor(acc, off, 64);
    __shared__ float wsum[4];
    if ((tid & 63) == 0) wsum[tid >> 6] = acc;
    __syncthreads();
    if (tid == 0) out[0] = wsum[0] + wsum[1] + wsum[2] + wsum[3];
}

extern "C" void kernel_launch(void* const* d_in, const int* in_sizes, int n_in,
                              void* d_out, int out_size, void* d_ws, size_t ws_size,
                              hipStream_t stream) {
    const float* node_feats = (const float*)d_in[0];
    const float* edge_vec   = (const float*)d_in[1];
    const float* W1         = (const float*)d_in[2];
    const float* W2         = (const float*)d_in[3];
    const int*   edge_src   = (const int*)d_in[4];
    // d_in[5] (edge_dst) unused: segment_sum().sum() == plain sum over edges.
    const int n_edges = in_sizes[4];
    const int n_nodes = in_sizes[0] / 9;

    // ws layout: [block_sums: 32KB][wtab: 3*NBP f32][packed table: N*16B]
    float* block_sums = (float*)d_ws;
    const size_t wtab_off = 32768;
    const size_t tab_off  = wtab_off + ((3 * NBP * 4 + 255) & ~255);   // 256-aligned
    const size_t need     = tab_off + (size_t)n_nodes * 16;

    if (ws_size >= need) {
        float* wtab = (float*)((char*)d_ws + wtab_off);
        uint4* tab  = (uint4*)((char*)d_ws + tab_off);
        pack_feats_14<<<(n_nodes + 255) / 256, 256, 0, stream>>>(
            node_feats, tab, n_nodes);
        build_wtable_kernel<<<(NB + 256) / 256, 256, 0, stream>>>(W1, W2, wtab);
        edge_sum_p14<<<NBLOCKS, NTHREADS, 0, stream>>>(
            (const float4*)edge_vec, (const int4*)edge_src, tab,
            wtab, block_sums, n_edges);
        final_reduce_kernel<<<1, 256, 0, stream>>>(block_sums, (float*)d_out, NBLOCKS);
    } else {
        edge_sum_fallback<<<FB_NBLOCKS, NTHREADS, 0, stream>>>(
            node_feats, edge_vec, W1, W2, edge_src, block_sums, n_edges);
        final_reduce_kernel<<<1, 256, 0, stream>>>(block_sums, (float*)d_out, FB_NBLOCKS);
    }
}